// Round 12
// baseline (136.328 us; speedup 1.0000x reference)
//
#include <hip/hip_runtime.h>

#define S_TOT 2048
#define BATCH 128
#define FEAT  256
#define CHUNK 32    // k-rows per pipeline stage (small LDS -> 2 blocks/CU)
#define ROWH  36    // 32 halves + 4 pad
#define GROWS 32    // rows per gather block

typedef _Float16 f16x4 __attribute__((ext_vector_type(4)));
typedef _Float16 f16x2 __attribute__((ext_vector_type(2)));
typedef float f32x4 __attribute__((ext_vector_type(4)));

// Fused stats + Gram via MFMA, double-buffered, QUARTER-split: 4 blocks per
// batch (64 Gram rows each), 512 blocks total -> 2 co-resident blocks/CU
// (41 KB LDS, ~55 VGPR, 32 waves/CU = cap). Co-residency hides the per-iter
// vmcnt-drain + barrier bubble that capped R11's cov at ~2x the HBM floor.
// XCD-quad grouping: all 4 blocks of batch b land on the same XCD so the
// 4x duplicate read of b's slice merges in that XCD's L2/MSHRs.
// Correlation is affine-invariant: stage RAW f16, MFMA the Gram, per-feature
// sum/sumsq of the SAME f16-rounded values in fp32, then threshold
// (G - n*mi*mj) / ((n-1)*si*sj) > 0.999.
// Ref's +1e-6 std shift scales cov by ~2e-6: irrelevant vs 1e-3 margins.
// sigma=0 features: is_=0 -> cv=0 -> never selected (matches ref).
__global__ __launch_bounds__(1024) void k_cov(
        const float* __restrict__ x, const int* __restrict__ sep,
        int* __restrict__ colsum_part) {
    const int d = blockIdx.x;                 // 0..511
    const int b = (d & 7) + 8 * (d >> 5);     // bijective: d>>5 in 0..15
    const int q = (d >> 3) & 3;               // quarter (same XCD for fixed b)
    const int n = sep[0];
    const int t = threadIdx.x;
    const int l = t & 63;
    const int w = t >> 6;                     // 0..15
    const int wr = w >> 2;                    // row-tile 0..3 within quarter
    const int wc = w & 3;                     // col-group 0..3 (64 cols)
    const int l15 = l & 15, lg = l >> 4;

    __shared__ _Float16 T[2][FEAT][ROWH];
    __shared__ float ms[FEAT], is_[FEAT];
    __shared__ int scount[FEAT];
    float* redf = (float*)&T[0][0][0];        // post-loop reuse: red[2][4][FEAT]

    // staging role: thread covers feature f, k-slots kg*8 .. kg*8+7
    const int f = t & 255;
    const int kg = t >> 8;                    // 0..3

    f32x4 acc[4];
#pragma unroll
    for (int c = 0; c < 4; ++c) acc[c] = (f32x4){0.f, 0.f, 0.f, 0.f};

    float psum = 0.f, psq = 0.f;
    float stage[8];

    const size_t xoff = (size_t)b * FEAT + f;
    const int NC = (n + CHUNK - 1) / CHUNK;

    if (t < FEAT) scount[t] = 0;

    // prologue: chunk 0 -> regs -> buf 0
    {
        const int k0 = kg * 8;
#pragma unroll
        for (int i = 0; i < 8; ++i) {
            const int s = k0 + i;
            stage[i] = (s < n) ? x[(size_t)s * (BATCH * FEAT) + xoff] : 0.f;
        }
#pragma unroll
        for (int i = 0; i < 8; i += 2) {
            _Float16 h0 = (_Float16)stage[i], h1 = (_Float16)stage[i + 1];
            float r0 = (float)h0, r1 = (float)h1;
            psum += r0 + r1;
            psq = fmaf(r0, r0, psq);
            psq = fmaf(r1, r1, psq);
            *(f16x2*)&T[0][f][k0 + i] = (f16x2){h0, h1};
        }
    }
    __syncthreads();

    for (int c = 0; c < NC; ++c) {
        const int cur = c & 1;
        const bool more = (c + 1 < NC);
        if (more) {
            const int k0 = (c + 1) * CHUNK + kg * 8;
#pragma unroll
            for (int i = 0; i < 8; ++i) {
                const int s = k0 + i;
                stage[i] = (s < n) ? x[(size_t)s * (BATCH * FEAT) + xoff] : 0.f;
            }
        }
        // MFMA on buf cur (prefetch loads drain under this)
#pragma unroll
        for (int ks = 0; ks < 2; ++ks) {
            const int kloc = ks * 16 + 4 * lg;
            f16x4 a = *(const f16x4*)&T[cur][q * 64 + wr * 16 + l15][kloc];
            f16x4 bb[4];
#pragma unroll
            for (int c2 = 0; c2 < 4; ++c2)
                bb[c2] = *(const f16x4*)&T[cur][wc * 64 + c2 * 16 + l15][kloc];
#pragma unroll
            for (int c2 = 0; c2 < 4; ++c2)
                acc[c2] = __builtin_amdgcn_mfma_f32_16x16x16f16(
                    a, bb[c2], acc[c2], 0, 0, 0);
        }
        if (more) {
            const int nxt = cur ^ 1;
            const int kb = kg * 8;
#pragma unroll
            for (int i = 0; i < 8; i += 2) {
                _Float16 h0 = (_Float16)stage[i], h1 = (_Float16)stage[i + 1];
                float r0 = (float)h0, r1 = (float)h1;
                psum += r0 + r1;
                psq = fmaf(r0, r0, psq);
                psq = fmaf(r1, r1, psq);
                *(f16x2*)&T[nxt][f][kb + i] = (f16x2){h0, h1};
            }
        }
        __syncthreads();
    }

    // fold per-feature partials (4 kg-threads/feature); redf overlays T[0]
    redf[kg * FEAT + f] = psum;
    redf[(4 + kg) * FEAT + f] = psq;
    __syncthreads();
    if (t < FEAT) {
        float s = redf[0 * FEAT + t] + redf[1 * FEAT + t] + redf[2 * FEAT + t] + redf[3 * FEAT + t];
        float qq = redf[4 * FEAT + t] + redf[5 * FEAT + t] + redf[6 * FEAT + t] + redf[7 * FEAT + t];
        float m = s / (float)n;
        float var = (qq - (float)n * m * m) / (float)(n - 1);
        ms[t] = m;
        is_[t] = (var > 0.f) ? rsqrtf(var) : 0.f;
    }
    __syncthreads();

    const float fn = (float)n;
    const float inv_nm1 = 1.f / (float)(n - 1);
#pragma unroll
    for (int c = 0; c < 4; ++c) {
        const int gj = wc * 64 + c * 16 + l15;
        const float mj = ms[gj], ij = is_[gj];
        int cnt = 0;
        const int gib = q * 64 + wr * 16 + 4 * lg;
#pragma unroll
        for (int e = 0; e < 4; ++e) {
            const int gi = gib + e;
            float cv = (acc[c][e] - fn * ms[gi] * mj) * inv_nm1 * is_[gi] * ij;
            if (gi <= gj && cv > 0.999f) cnt++;
        }
        if (cnt) atomicAdd(&scount[gj], cnt);
    }
    __syncthreads();
    if (t < FEAT) colsum_part[(q * BATCH + b) * FEAT + t] = scount[t];
}

// stable order (selected features first) + counts, ballot prefix.
// Sums the four per-quarter partial counts (no memset / global atomics).
__global__ void k_select(const int* __restrict__ colsum_part, int* __restrict__ order,
                         int* __restrict__ counts) {
    __shared__ int wsum[4];
    const int b = blockIdx.x;
    const int j = threadIdx.x;         // 0..255
    const int cs = colsum_part[b * FEAT + j] +
                   colsum_part[(BATCH + b) * FEAT + j] +
                   colsum_part[(2 * BATCH + b) * FEAT + j] +
                   colsum_part[(3 * BATCH + b) * FEAT + j];
    const int sel = (cs == 1) ? 1 : 0;
    unsigned long long mask = __ballot(sel);
    const int lane = j & 63;
    const int wid = j >> 6;
    int pre = __popcll(mask & ((1ull << lane) - 1ull));
    if (lane == 0) wsum[wid] = __popcll(mask);
    __syncthreads();
    int woff = 0;
#pragma unroll
    for (int w = 0; w < 4; ++w) woff += (w < wid) ? wsum[w] : 0;
    const int total = wsum[0] + wsum[1] + wsum[2] + wsum[3];
    if (sel) {
        order[b * FEAT + woff + pre] = j;
    } else {
        int unsel_pre = j - (woff + pre);
        order[b * FEAT + total + unsel_pre] = j;
    }
    if (j == 0) counts[b] = total;
}

// gather through LDS: stage GROWS rows coalesced (float4), permute in LDS,
// store contiguous float4 nontemporal. Grid is b-fastest so consecutive
// blocks stream contiguous HBM (128 blocks cover 32 full rows = 4 MB).
__global__ __launch_bounds__(512) void k_gather(
        const float* __restrict__ x, const int* __restrict__ order,
        const int* __restrict__ counts, float* __restrict__ out) {
    const int b = blockIdx.x;
    const int s0 = blockIdx.y * GROWS;
    const int t = threadIdx.x;          // 0..511

    __shared__ float T[GROWS][FEAT];
    __shared__ int ord_s[FEAT];
    __shared__ int cnt_s;

    if (t < FEAT) ord_s[t] = order[b * FEAT + t];
    if (t == 0) cnt_s = counts[b];

    const size_t bbase = (size_t)b * FEAT;
#pragma unroll
    for (int i = 0; i < (GROWS * FEAT) / (512 * 4); ++i) {  // 4 float4/thread
        const int idx = i * 512 + t;        // 0..2047
        const int row = idx >> 6;           // 64 float4 per row
        const int f4 = (idx & 63) * 4;
        float4 v = *(const float4*)&x[(size_t)(s0 + row) * (BATCH * FEAT) + bbase + f4];
        *(float4*)&T[row][f4] = v;
    }
    __syncthreads();

    const int c4 = (t & 63) * 4;
    const int tr = t >> 6;               // 0..7
    const int cnt = cnt_s;
    const int o0 = ord_s[c4 + 0], o1 = ord_s[c4 + 1];
    const int o2 = ord_s[c4 + 2], o3 = ord_s[c4 + 3];
#pragma unroll
    for (int r = tr; r < GROWS; r += 8) {
        f32x4 v;
        v.x = (c4 + 0 < cnt) ? T[r][o0] : 0.f;
        v.y = (c4 + 1 < cnt) ? T[r][o1] : 0.f;
        v.z = (c4 + 2 < cnt) ? T[r][o2] : 0.f;
        v.w = (c4 + 3 < cnt) ? T[r][o3] : 0.f;
        __builtin_nontemporal_store(v,
            (f32x4*)&out[(size_t)(s0 + r) * (BATCH * FEAT) + bbase + c4]);
    }
}

extern "C" void kernel_launch(void* const* d_in, const int* in_sizes, int n_in,
                              void* d_out, int out_size, void* d_ws, size_t ws_size,
                              hipStream_t stream) {
    const float* x = (const float*)d_in[0];
    const int* sep = (const int*)d_in[1];
    float* out = (float*)d_out;

    int* colsum_part = (int*)d_ws;                     // [4][BATCH][FEAT]
    int* order = colsum_part + 4 * BATCH * FEAT;
    int* counts = order + BATCH * FEAT;

    k_cov<<<dim3(4 * BATCH), dim3(1024), 0, stream>>>(x, sep, colsum_part);

    k_select<<<dim3(BATCH), dim3(FEAT), 0, stream>>>(colsum_part, order, counts);

    k_gather<<<dim3(BATCH, S_TOT / GROWS), dim3(512), 0, stream>>>(x, order, counts, out);
}

// Round 13
// 122.115 us; speedup vs baseline: 1.1164x; 1.1164x over previous
//
#include <hip/hip_runtime.h>

#define S_TOT 2048
#define BATCH 128
#define FEAT  256
#define CHUNK 64    // k-rows per pipeline stage
#define ROWH  68    // 64 halves + 4 pad; 136 B row stride
#define GROWS 16    // rows per gather block

typedef _Float16 f16x4 __attribute__((ext_vector_type(4)));
typedef _Float16 f16x2 __attribute__((ext_vector_type(2)));
typedef float f32x4 __attribute__((ext_vector_type(4)));

// Fused stats + Gram via MFMA, double-buffered, row-split 2 blocks/batch
// (R11 structure — R12's quarter-split doubled duplicate reads, reverted).
// NEW: staging is f4-vectorized — each thread owns 4 features x 4 rows per
// chunk, loading 4 coalesced dwordx4 instead of 16 stride-1KB scalar dwords
// (R11's vmem-issue train was the suspect for cov's 2x-over-HBM-floor).
// XCD-pair swizzle: both halves of batch b on the same XCD for L2 dedup.
// Correlation is affine-invariant: stage RAW f16, MFMA the Gram, per-feature
// sum/sumsq of the SAME f16-rounded values in fp32, then threshold
// (G - n*mi*mj) / ((n-1)*si*sj) > 0.999.
// Ref's +1e-6 std shift scales cov by ~2e-6: irrelevant vs 1e-3 margins.
// sigma=0 features: is_=0 -> cv=0 -> never selected (matches ref).
__global__ __launch_bounds__(1024) void k_cov(
        const float* __restrict__ x, const int* __restrict__ sep,
        int* __restrict__ colsum_part) {
    const int d = blockIdx.x;               // 0..255
    const int b = (d & 7) + 8 * (d >> 4);   // XCD-pair remap (bijective)
    const int half = (d >> 3) & 1;          // halves of b are 8 slots apart
    const int n = sep[0];
    const int t = threadIdx.x;
    const int l = t & 63;
    const int w = t >> 6;               // 0..15; wave tile = 32 rows x 64 cols
    const int wm = w >> 2, wn = w & 3;
    const int l15 = l & 15, lg = l >> 4;

    __shared__ _Float16 T[2][FEAT][ROWH];
    __shared__ float ms[FEAT], is_[FEAT];
    __shared__ int scount[FEAT];
    float* redf = (float*)&T[0][0][0];  // post-loop overlay: [2][16][FEAT]

    // staging role: thread covers features f4..f4+3, chunk-rows
    // {2w, 2w+1, 2w+32, 2w+33}  (w = wave id = row-pair index)
    const int fg = t & 63;
    const int f4 = fg * 4;

    f32x4 acc[2][4];
#pragma unroll
    for (int r = 0; r < 2; ++r)
#pragma unroll
        for (int c = 0; c < 4; ++c)
            acc[r][c] = (f32x4){0.f, 0.f, 0.f, 0.f};

    float psum[4] = {0.f, 0.f, 0.f, 0.f};
    float psq[4] = {0.f, 0.f, 0.f, 0.f};
    f32x4 stA0, stA1, stB0, stB1;

    const size_t colbase = (size_t)b * FEAT + f4;
    const int NC = (n + CHUNK - 1) / CHUNK;

    if (t < FEAT) scount[t] = 0;

#define LOADC(c)                                                            \
    {                                                                       \
        const int r0 = (c) * CHUNK + 2 * w;                                 \
        const f32x4 z = (f32x4){0.f, 0.f, 0.f, 0.f};                        \
        stA0 = (r0 + 0 < n) ? *(const f32x4*)&x[(size_t)(r0 + 0) * (BATCH * FEAT) + colbase] : z; \
        stA1 = (r0 + 1 < n) ? *(const f32x4*)&x[(size_t)(r0 + 1) * (BATCH * FEAT) + colbase] : z; \
        stB0 = (r0 + 32 < n) ? *(const f32x4*)&x[(size_t)(r0 + 32) * (BATCH * FEAT) + colbase] : z; \
        stB1 = (r0 + 33 < n) ? *(const f32x4*)&x[(size_t)(r0 + 33) * (BATCH * FEAT) + colbase] : z; \
    }

#define CVTC(buf)                                                           \
    {                                                                       \
        _Pragma("unroll")                                                   \
        for (int j = 0; j < 4; ++j) {                                       \
            _Float16 h0 = (_Float16)stA0[j], h1 = (_Float16)stA1[j];        \
            _Float16 h2 = (_Float16)stB0[j], h3 = (_Float16)stB1[j];        \
            float r0 = (float)h0, r1 = (float)h1, r2 = (float)h2, r3 = (float)h3; \
            psum[j] += (r0 + r1) + (r2 + r3);                               \
            psq[j] = fmaf(r0, r0, psq[j]);                                  \
            psq[j] = fmaf(r1, r1, psq[j]);                                  \
            psq[j] = fmaf(r2, r2, psq[j]);                                  \
            psq[j] = fmaf(r3, r3, psq[j]);                                  \
            *(f16x2*)&T[buf][f4 + j][2 * w] = (f16x2){h0, h1};              \
            *(f16x2*)&T[buf][f4 + j][2 * w + 32] = (f16x2){h2, h3};         \
        }                                                                   \
    }

    // prologue: chunk 0 -> regs -> buf 0
    LOADC(0);
    CVTC(0);
    __syncthreads();

    for (int c = 0; c < NC; ++c) {
        const int cur = c & 1;
        const bool more = (c + 1 < NC);
        if (more) LOADC(c + 1);
        // MFMA on buf cur (prefetch loads drain under this)
#pragma unroll
        for (int ks = 0; ks < 4; ++ks) {
            const int kloc = ks * 16 + 4 * lg;
            f16x4 a[2], bb[4];
#pragma unroll
            for (int r = 0; r < 2; ++r)
                a[r] = *(const f16x4*)&T[cur][half * 128 + wm * 32 + r * 16 + l15][kloc];
#pragma unroll
            for (int c2 = 0; c2 < 4; ++c2)
                bb[c2] = *(const f16x4*)&T[cur][wn * 64 + c2 * 16 + l15][kloc];
#pragma unroll
            for (int r = 0; r < 2; ++r)
#pragma unroll
                for (int c2 = 0; c2 < 4; ++c2)
                    acc[r][c2] = __builtin_amdgcn_mfma_f32_16x16x16f16(
                        a[r], bb[c2], acc[r][c2], 0, 0, 0);
        }
        if (more) {
            const int nxt = cur ^ 1;
            CVTC(nxt);
        }
        __syncthreads();
    }

    // fold per-feature partials: wave w holds rows-of-chunk partials for
    // features f4..f4+3; sum over the 16 waves. redf overlays T.
#pragma unroll
    for (int j = 0; j < 4; ++j) {
        redf[w * FEAT + f4 + j] = psum[j];
        redf[16 * FEAT + w * FEAT + f4 + j] = psq[j];
    }
    __syncthreads();
    if (t < FEAT) {
        float s = 0.f, q = 0.f;
#pragma unroll
        for (int k = 0; k < 16; ++k) {
            s += redf[k * FEAT + t];
            q += redf[16 * FEAT + k * FEAT + t];
        }
        float m = s / (float)n;
        float var = (q - (float)n * m * m) / (float)(n - 1);
        ms[t] = m;
        is_[t] = (var > 0.f) ? rsqrtf(var) : 0.f;
    }
    __syncthreads();

    const float fn = (float)n;
    const float inv_nm1 = 1.f / (float)(n - 1);
#pragma unroll
    for (int c = 0; c < 4; ++c) {
        const int gj = wn * 64 + c * 16 + l15;
        const float mj = ms[gj], ij = is_[gj];
        int cnt = 0;
#pragma unroll
        for (int r = 0; r < 2; ++r) {
            const int gib = half * 128 + wm * 32 + r * 16 + 4 * lg;
#pragma unroll
            for (int q = 0; q < 4; ++q) {
                const int gi = gib + q;
                float cv = (acc[r][c][q] - fn * ms[gi] * mj) * inv_nm1 * is_[gi] * ij;
                if (gi <= gj && cv > 0.999f) cnt++;
            }
        }
        if (cnt) atomicAdd(&scount[gj], cnt);
    }
    __syncthreads();
    if (t < FEAT) colsum_part[(half * BATCH + b) * FEAT + t] = scount[t];
}

// stable order (selected features first) + counts, ballot prefix.
// Sums the two per-half partial counts (no memset / global atomics).
__global__ void k_select(const int* __restrict__ colsum_part, int* __restrict__ order,
                         int* __restrict__ counts) {
    __shared__ int wsum[4];
    const int b = blockIdx.x;
    const int j = threadIdx.x;         // 0..255
    const int cs = colsum_part[b * FEAT + j] +
                   colsum_part[(BATCH + b) * FEAT + j];
    const int sel = (cs == 1) ? 1 : 0;
    unsigned long long mask = __ballot(sel);
    const int lane = j & 63;
    const int wid = j >> 6;
    int pre = __popcll(mask & ((1ull << lane) - 1ull));
    if (lane == 0) wsum[wid] = __popcll(mask);
    __syncthreads();
    int woff = 0;
#pragma unroll
    for (int w = 0; w < 4; ++w) woff += (w < wid) ? wsum[w] : 0;
    const int total = wsum[0] + wsum[1] + wsum[2] + wsum[3];
    if (sel) {
        order[b * FEAT + woff + pre] = j;
    } else {
        int unsel_pre = j - (woff + pre);
        order[b * FEAT + total + unsel_pre] = j;
    }
    if (j == 0) counts[b] = total;
}

// gather: if counts[b]==FEAT the stable order is provably the identity ->
// block-uniform fast path = pure NT float4 copy (no LDS). Otherwise LDS
// permute path. Grid is b-fastest: consecutive blocks stream 2 MB contiguous.
__global__ __launch_bounds__(256) void k_gather(
        const float* __restrict__ x, const int* __restrict__ order,
        const int* __restrict__ counts, float* __restrict__ out) {
    const int b = blockIdx.x;
    const int s0 = blockIdx.y * GROWS;
    const int t = threadIdx.x;

    __shared__ float T[GROWS][FEAT];
    __shared__ int ord_s[FEAT];
    __shared__ int cnt_s;

    ord_s[t] = order[b * FEAT + t];
    if (t == 0) cnt_s = counts[b];
    __syncthreads();

    const int cnt = cnt_s;
    const size_t bbase = (size_t)b * FEAT;

    if (cnt == FEAT) {
        // identity permutation, no masking: straight copy
#pragma unroll
        for (int i = 0; i < (GROWS * FEAT) / (256 * 4); ++i) {
            const int idx = i * 256 + t;
            const int row = idx >> 6;
            const int f4 = (idx & 63) * 4;
            const size_t off = (size_t)(s0 + row) * (BATCH * FEAT) + bbase + f4;
            f32x4 v = *(const f32x4*)&x[off];
            __builtin_nontemporal_store(v, (f32x4*)&out[off]);
        }
        return;
    }

#pragma unroll
    for (int i = 0; i < (GROWS * FEAT) / (256 * 4); ++i) {  // 4 float4/thread
        const int idx = i * 256 + t;
        const int row = idx >> 6;
        const int f4 = (idx & 63) * 4;
        float4 v = *(const float4*)&x[(size_t)(s0 + row) * (BATCH * FEAT) + bbase + f4];
        *(float4*)&T[row][f4] = v;
    }
    __syncthreads();

    const int c4 = (t & 63) * 4;
    const int tr = t >> 6;               // 0..3
    const int o0 = ord_s[c4 + 0], o1 = ord_s[c4 + 1];
    const int o2 = ord_s[c4 + 2], o3 = ord_s[c4 + 3];
#pragma unroll
    for (int r = tr; r < GROWS; r += 4) {
        f32x4 v;
        v.x = (c4 + 0 < cnt) ? T[r][o0] : 0.f;
        v.y = (c4 + 1 < cnt) ? T[r][o1] : 0.f;
        v.z = (c4 + 2 < cnt) ? T[r][o2] : 0.f;
        v.w = (c4 + 3 < cnt) ? T[r][o3] : 0.f;
        __builtin_nontemporal_store(v,
            (f32x4*)&out[(size_t)(s0 + r) * (BATCH * FEAT) + bbase + c4]);
    }
}

extern "C" void kernel_launch(void* const* d_in, const int* in_sizes, int n_in,
                              void* d_out, int out_size, void* d_ws, size_t ws_size,
                              hipStream_t stream) {
    const float* x = (const float*)d_in[0];
    const int* sep = (const int*)d_in[1];
    float* out = (float*)d_out;

    int* colsum_part = (int*)d_ws;                     // [2][BATCH][FEAT]
    int* order = colsum_part + 2 * BATCH * FEAT;
    int* counts = order + BATCH * FEAT;

    k_cov<<<dim3(2 * BATCH), dim3(1024), 0, stream>>>(x, sep, colsum_part);

    k_select<<<dim3(BATCH), dim3(FEAT), 0, stream>>>(colsum_part, order, counts);

    k_gather<<<dim3(BATCH, S_TOT / GROWS), dim3(256), 0, stream>>>(x, order, counts, out);
}

// Round 14
// 118.693 us; speedup vs baseline: 1.1486x; 1.0288x over previous
//
#include <hip/hip_runtime.h>

#define S_TOT 2048
#define BATCH 128
#define FEAT  256
#define CHUNK 64    // k-rows per pipeline stage
#define ROWH  68    // 64 halves + 4 pad; 136 B row stride
#define GROWS 16    // rows per gather block

typedef _Float16 f16x4 __attribute__((ext_vector_type(4)));
typedef _Float16 f16x2 __attribute__((ext_vector_type(2)));
typedef float f32x4 __attribute__((ext_vector_type(4)));

// Fused stats + Gram via MFMA, row-split 2 blocks/batch, XCD-pair swizzle,
// NEW: 2-deep register staging (sets A/B, static roles via unroll-by-2) so
// chunk c+2's loads are consumed a full sub-iteration after issue — R13's
// 1-deep pipeline exposed ~1us of HBM latency per iter (33 vs 21us floor).
// Correlation is affine-invariant: stage RAW f16, MFMA the Gram, per-feature
// sum/sumsq of the SAME f16-rounded values in fp32, then threshold
// (G - n*mi*mj) / ((n-1)*si*sj) > 0.999.
// Ref's +1e-6 std shift scales cov by ~2e-6: irrelevant vs 1e-3 margins.
// sigma=0 features: is_=0 -> cv=0 -> never selected (matches ref).
__global__ __launch_bounds__(1024) void k_cov(
        const float* __restrict__ x, const int* __restrict__ sep,
        int* __restrict__ colsum_part) {
    const int d = blockIdx.x;               // 0..255
    const int b = (d & 7) + 8 * (d >> 4);   // XCD-pair remap (bijective)
    const int half = (d >> 3) & 1;          // halves of b are 8 slots apart
    const int n = sep[0];
    const int t = threadIdx.x;
    const int l = t & 63;
    const int w = t >> 6;               // 0..15; wave tile = 32 rows x 64 cols
    const int wm = w >> 2, wn = w & 3;
    const int l15 = l & 15, lg = l >> 4;

    __shared__ _Float16 T[2][FEAT][ROWH];
    __shared__ float ms[FEAT], is_[FEAT];
    __shared__ int scount[FEAT];
    float* redf = (float*)&T[0][0][0];  // post-loop overlay: [2][16][FEAT]

    // staging role: thread covers features f4..f4+3, chunk-rows
    // {2w, 2w+1, 2w+32, 2w+33}  (w = wave id = row-pair index)
    const int fg = t & 63;
    const int f4 = fg * 4;

    f32x4 acc[2][4];
#pragma unroll
    for (int r = 0; r < 2; ++r)
#pragma unroll
        for (int c = 0; c < 4; ++c)
            acc[r][c] = (f32x4){0.f, 0.f, 0.f, 0.f};

    float psum[4] = {0.f, 0.f, 0.f, 0.f};
    float psq[4] = {0.f, 0.f, 0.f, 0.f};
    f32x4 sA0, sA1, sA2, sA3;   // stage set A
    f32x4 sB0, sB1, sB2, sB3;   // stage set B

    const size_t colbase = (size_t)b * FEAT + f4;
    const int NC = (n + CHUNK - 1) / CHUNK;

    if (t < FEAT) scount[t] = 0;

#define LOADC(c, S0, S1, S2, S3)                                            \
    {                                                                       \
        const int r0 = (c) * CHUNK + 2 * w;                                 \
        const f32x4 z = (f32x4){0.f, 0.f, 0.f, 0.f};                        \
        S0 = (r0 + 0 < n) ? *(const f32x4*)&x[(size_t)(r0 + 0) * (BATCH * FEAT) + colbase] : z; \
        S1 = (r0 + 1 < n) ? *(const f32x4*)&x[(size_t)(r0 + 1) * (BATCH * FEAT) + colbase] : z; \
        S2 = (r0 + 32 < n) ? *(const f32x4*)&x[(size_t)(r0 + 32) * (BATCH * FEAT) + colbase] : z; \
        S3 = (r0 + 33 < n) ? *(const f32x4*)&x[(size_t)(r0 + 33) * (BATCH * FEAT) + colbase] : z; \
    }

#define CVTC(buf, S0, S1, S2, S3)                                           \
    {                                                                       \
        _Pragma("unroll")                                                   \
        for (int j = 0; j < 4; ++j) {                                       \
            _Float16 h0 = (_Float16)S0[j], h1 = (_Float16)S1[j];            \
            _Float16 h2 = (_Float16)S2[j], h3 = (_Float16)S3[j];            \
            float r0 = (float)h0, r1 = (float)h1, r2 = (float)h2, r3 = (float)h3; \
            psum[j] += (r0 + r1) + (r2 + r3);                               \
            psq[j] = fmaf(r0, r0, psq[j]);                                  \
            psq[j] = fmaf(r1, r1, psq[j]);                                  \
            psq[j] = fmaf(r2, r2, psq[j]);                                  \
            psq[j] = fmaf(r3, r3, psq[j]);                                  \
            *(f16x2*)&T[buf][f4 + j][2 * w] = (f16x2){h0, h1};              \
            *(f16x2*)&T[buf][f4 + j][2 * w + 32] = (f16x2){h2, h3};         \
        }                                                                   \
    }

#define MFMAC(buf)                                                          \
    {                                                                       \
        _Pragma("unroll")                                                   \
        for (int ks = 0; ks < 4; ++ks) {                                    \
            const int kloc = ks * 16 + 4 * lg;                              \
            f16x4 a[2], bb[4];                                              \
            _Pragma("unroll")                                               \
            for (int r = 0; r < 2; ++r)                                     \
                a[r] = *(const f16x4*)&T[buf][half * 128 + wm * 32 + r * 16 + l15][kloc]; \
            _Pragma("unroll")                                               \
            for (int c2 = 0; c2 < 4; ++c2)                                  \
                bb[c2] = *(const f16x4*)&T[buf][wn * 64 + c2 * 16 + l15][kloc]; \
            _Pragma("unroll")                                               \
            for (int r = 0; r < 2; ++r)                                     \
                _Pragma("unroll")                                           \
                for (int c2 = 0; c2 < 4; ++c2)                              \
                    acc[r][c2] = __builtin_amdgcn_mfma_f32_16x16x16f16(     \
                        a[r], bb[c2], acc[r][c2], 0, 0, 0);                 \
        }                                                                   \
    }

    // prologue: chunk0 -> A -> T[0]; chunk1 -> B
    LOADC(0, sA0, sA1, sA2, sA3);
    CVTC(0, sA0, sA1, sA2, sA3);
    LOADC(1, sB0, sB1, sB2, sB3);
    __syncthreads();

    for (int c = 0; c < NC; c += 2) {
        // sub-iter even: chunk c in T[0]
        if (c + 2 < NC) LOADC(c + 2, sA0, sA1, sA2, sA3);
        MFMAC(0);
        if (c + 1 < NC) CVTC(1, sB0, sB1, sB2, sB3);
        __syncthreads();
        // sub-iter odd: chunk c+1 in T[1]
        if (c + 1 < NC) {
            if (c + 3 < NC) LOADC(c + 3, sB0, sB1, sB2, sB3);
            MFMAC(1);
            if (c + 2 < NC) CVTC(0, sA0, sA1, sA2, sA3);
            __syncthreads();
        }
    }

    // fold per-feature partials: wave w holds partials for features f4..f4+3
#pragma unroll
    for (int j = 0; j < 4; ++j) {
        redf[w * FEAT + f4 + j] = psum[j];
        redf[16 * FEAT + w * FEAT + f4 + j] = psq[j];
    }
    __syncthreads();
    if (t < FEAT) {
        float s = 0.f, q = 0.f;
#pragma unroll
        for (int k = 0; k < 16; ++k) {
            s += redf[k * FEAT + t];
            q += redf[16 * FEAT + k * FEAT + t];
        }
        float m = s / (float)n;
        float var = (q - (float)n * m * m) / (float)(n - 1);
        ms[t] = m;
        is_[t] = (var > 0.f) ? rsqrtf(var) : 0.f;
    }
    __syncthreads();

    const float fn = (float)n;
    const float inv_nm1 = 1.f / (float)(n - 1);
#pragma unroll
    for (int c = 0; c < 4; ++c) {
        const int gj = wn * 64 + c * 16 + l15;
        const float mj = ms[gj], ij = is_[gj];
        int cnt = 0;
#pragma unroll
        for (int r = 0; r < 2; ++r) {
            const int gib = half * 128 + wm * 32 + r * 16 + 4 * lg;
#pragma unroll
            for (int q = 0; q < 4; ++q) {
                const int gi = gib + q;
                float cv = (acc[r][c][q] - fn * ms[gi] * mj) * inv_nm1 * is_[gi] * ij;
                if (gi <= gj && cv > 0.999f) cnt++;
            }
        }
        if (cnt) atomicAdd(&scount[gj], cnt);
    }
    __syncthreads();
    if (t < FEAT) colsum_part[(half * BATCH + b) * FEAT + t] = scount[t];
}

// gather with FUSED select: each block recomputes the stable ballot-order
// from colsum_part (2 KB L2-hit read + ~50 instrs) — kills the separate
// select dispatch. counts==FEAT => identity permutation, no mask => pure
// NT float4 copy (no LDS). Grid b-fastest: consecutive blocks stream
// contiguous HBM.
__global__ __launch_bounds__(256) void k_gather(
        const float* __restrict__ x, const int* __restrict__ colsum_part,
        float* __restrict__ out) {
    const int b = blockIdx.x;
    const int s0 = blockIdx.y * GROWS;
    const int t = threadIdx.x;          // 0..255 == feature j

    __shared__ float T[GROWS][FEAT];
    __shared__ int ord_s[FEAT];
    __shared__ int wsum[4];

    // inline stable select (identical math to the old k_select)
    const int cs = colsum_part[b * FEAT + t] +
                   colsum_part[(BATCH + b) * FEAT + t];
    const int sel = (cs == 1) ? 1 : 0;
    unsigned long long mask = __ballot(sel);
    const int lane = t & 63;
    const int wid = t >> 6;
    int pre = __popcll(mask & ((1ull << lane) - 1ull));
    if (lane == 0) wsum[wid] = __popcll(mask);
    __syncthreads();
    int woff = 0;
#pragma unroll
    for (int w = 0; w < 4; ++w) woff += (w < wid) ? wsum[w] : 0;
    const int total = wsum[0] + wsum[1] + wsum[2] + wsum[3];
    if (sel) {
        ord_s[woff + pre] = t;
    } else {
        ord_s[total + (t - woff - pre)] = t;
    }

    const size_t bbase = (size_t)b * FEAT;

    if (total == FEAT) {
        // identity permutation, no masking: straight NT copy
#pragma unroll
        for (int i = 0; i < (GROWS * FEAT) / (256 * 4); ++i) {
            const int idx = i * 256 + t;
            const int row = idx >> 6;
            const int f4 = (idx & 63) * 4;
            const size_t off = (size_t)(s0 + row) * (BATCH * FEAT) + bbase + f4;
            f32x4 v = *(const f32x4*)&x[off];
            __builtin_nontemporal_store(v, (f32x4*)&out[off]);
        }
        return;
    }

    __syncthreads();   // ord_s ready (slow path only)

#pragma unroll
    for (int i = 0; i < (GROWS * FEAT) / (256 * 4); ++i) {  // 4 float4/thread
        const int idx = i * 256 + t;
        const int row = idx >> 6;
        const int f4 = (idx & 63) * 4;
        float4 v = *(const float4*)&x[(size_t)(s0 + row) * (BATCH * FEAT) + bbase + f4];
        *(float4*)&T[row][f4] = v;
    }
    __syncthreads();

    const int c4 = (t & 63) * 4;
    const int tr = t >> 6;               // 0..3
    const int o0 = ord_s[c4 + 0], o1 = ord_s[c4 + 1];
    const int o2 = ord_s[c4 + 2], o3 = ord_s[c4 + 3];
#pragma unroll
    for (int r = tr; r < GROWS; r += 4) {
        f32x4 v;
        v.x = (c4 + 0 < total) ? T[r][o0] : 0.f;
        v.y = (c4 + 1 < total) ? T[r][o1] : 0.f;
        v.z = (c4 + 2 < total) ? T[r][o2] : 0.f;
        v.w = (c4 + 3 < total) ? T[r][o3] : 0.f;
        __builtin_nontemporal_store(v,
            (f32x4*)&out[(size_t)(s0 + r) * (BATCH * FEAT) + bbase + c4]);
    }
}

extern "C" void kernel_launch(void* const* d_in, const int* in_sizes, int n_in,
                              void* d_out, int out_size, void* d_ws, size_t ws_size,
                              hipStream_t stream) {
    const float* x = (const float*)d_in[0];
    const int* sep = (const int*)d_in[1];
    float* out = (float*)d_out;

    int* colsum_part = (int*)d_ws;                     // [2][BATCH][FEAT]

    k_cov<<<dim3(2 * BATCH), dim3(1024), 0, stream>>>(x, sep, colsum_part);

    k_gather<<<dim3(BATCH, S_TOT / GROWS), dim3(256), 0, stream>>>(x, colsum_part, out);
}